// Round 4
// baseline (402.406 us; speedup 1.0000x reference)
//
#include <hip/hip_runtime.h>
#include <math.h>

// BoundaryFocalLoss: B=128, T=200000, f32 inputs, i32 targets, f32 mask -> scalar f32.
// ~307 MB footprint; L3 serves ~half (FETCH ~155 MB) so floor ~35-45 us.
//
// R1: 654 us = same-address atomic serialization -> partials + 2nd kernel (124 us).
// R2: latency-bound (16% HBM, 4 blocks/CU). R3: more blocks/MLP -> neutral (119 us):
//   VGPR=28 shows compiler serialized the 8 loads; 2560 blocks = 1.25 batches of the
//   8192-wave machine -> full batch + 25%-residency tail batch (measured occ 66%).
// R4: exact fill (2048 blocks = 32 waves/CU, single batch), __launch_bounds__(256,8)
//   for a 64-VGPR budget (keeps an iter's 8 loads in flight, 8 waves/SIMD), peeled
//   tail iter, VALU trims (window-OR for boundary, adaptive = 1.5 - sigmoid(|x|),
//   raw rcp).

#define B_DIM 128
#define T_DIM 200000

constexpr int BLOCK          = 256;
constexpr int GROUPS_PER_ROW = T_DIM / 4;          // 50000 int4/float4 groups
constexpr int CHUNKS_PER_ROW = T_DIM / 8;          // 25000 8-elem chunks
constexpr int BLOCKS_X       = 16;                 // 16*128 = 2048 blocks = 8192 waves
constexpr int ROW_STRIDE     = BLOCKS_X * BLOCK;   // 4096 chunks per sweep
constexpr int FULL_ITERS     = CHUNKS_PER_ROW / ROW_STRIDE;   // 6 (24576 chunks)
constexpr int NUM_PARTIALS   = BLOCKS_X * B_DIM;   // 2048

__device__ __forceinline__ void process_chunk(
    const float4* __restrict__ inp4,
    const float4* __restrict__ msk4,
    const int4*   __restrict__ tgt4,
    int q,                       // int4-group index (chunk*2)
    float& lsum, float& msum)
{
    // 8 loads, all issued before use (guarded halo loads use clamped addresses,
    // values fixed by select -> always straight-line, no OOB).
    const float4 x0 = inp4[q];
    const float4 x1 = inp4[q + 1];
    const float4 m0 = msk4[q];
    const float4 m1 = msk4[q + 1];
    const int4   c0 = tgt4[q];
    const int4   c1 = tgt4[q + 1];
    const int4   pvl = tgt4[(q > 0) ? q - 1 : 0];
    const int4   nxl = tgt4[(q + 2 < GROUPS_PER_ROW) ? q + 2 : GROUPS_PER_ROW - 2];

    const int4 pv = (q > 0) ? pvl : make_int4(c0.x, c0.x, c0.x, c0.x);
    const int4 nx = (q + 2 < GROUPS_PER_ROW) ? nxl : make_int4(c1.w, c1.w, c1.w, c1.w);

    // tg[k] = targets[t0 - 4 + k], k = 0..14 (halo -4..+10).
    // Clamp-replication zeroes edge transition bits, matching the reference's
    // zero-padded trans[0] and the 'SAME' window clipping.
    const int tg[15] = {pv.x, pv.y, pv.z, pv.w,
                        c0.x, c0.y, c0.z, c0.w,
                        c1.x, c1.y, c1.z, c1.w,
                        nx.x, nx.y, nx.z};

    unsigned mbits = 0u;
    #pragma unroll
    for (int k = 1; k <= 14; ++k) {
        if (tg[k] != tg[k - 1]) mbits |= (1u << k);
    }
    // window-OR: o[k] = OR of mbits[k .. k+6]; boundary_i = bit (i+1) of o
    unsigned o = mbits | (mbits >> 1);   // d = 0..1
    o |= o >> 2;                         // d = 0..3
    o |= o >> 3;                         // d = 0..6

    const float xs[8] = {x0.x, x0.y, x0.z, x0.w, x1.x, x1.y, x1.z, x1.w};
    const float ms[8] = {m0.x, m0.y, m0.z, m0.w, m1.x, m1.y, m1.z, m1.w};

    #pragma unroll
    for (int ii = 0; ii < 8; ++ii) {
        const float x  = xs[ii];
        const float mm = ms[ii];
        const float tf = (float)tg[4 + ii];
        const float posf = (tf > 0.5f) ? 1.0f : 0.0f;

        const float smoothed = fmaf(posf, 0.95f, 0.025f);   // pos*(1-ls)+ls/2
        const float alpha_w  = fmaf(posf, -0.5f, 0.75f);    // 0.25*pos+0.75*(1-pos)
        const float bf = (float)((o >> (ii + 1)) & 1u);
        const float w  = fmaf(bf, 4.0f, 1.0f);              // 1 or 5

        // ea = exp(-|x|); r = sigmoid(|x|); |sigmoid(x)-0.5| = r - 0.5
        const float ea   = __expf(-fabsf(x));
        const float opea = 1.0f + ea;
        const float r    = __builtin_amdgcn_rcpf(opea);
        const float adaptive = 1.5f - r;

        const float bce = fmaf(-x, smoothed, fmaxf(x, 0.0f)) + __logf(opea);
        const float pt  = __expf(-bce);
        const float om  = 1.0f - pt;

        const float t1 = alpha_w * om;
        const float t2 = t1 * om;
        const float t3 = t2 * bce;
        const float t4 = t3 * w;
        const float t5 = t4 * adaptive;
        lsum = fmaf(t5, mm, lsum);
        msum += mm;
    }
}

__global__ __launch_bounds__(BLOCK, 8) void bfl_main(
    const float* __restrict__ inputs,
    const int*   __restrict__ targets,
    const float* __restrict__ mask,
    float2*      __restrict__ partials)   // [NUM_PARTIALS] = (loss_sum, mask_sum)
{
    const int b = blockIdx.y;
    const long long row = (long long)b * T_DIM;
    const float4* __restrict__ inp4 = (const float4*)(inputs + row);
    const float4* __restrict__ msk4 = (const float4*)(mask + row);
    const int4*   __restrict__ tgt4 = (const int4*)(targets + row);

    const int base = blockIdx.x * BLOCK + threadIdx.x;

    float lsum = 0.0f, msum = 0.0f;

    #pragma unroll
    for (int iter = 0; iter < FULL_ITERS; ++iter) {
        process_chunk(inp4, msk4, tgt4, (iter * ROW_STRIDE + base) * 2, lsum, msum);
    }
    // peeled tail: chunks [24576, 25000)
    {
        const int chunk = FULL_ITERS * ROW_STRIDE + base;
        if (chunk < CHUNKS_PER_ROW) {
            process_chunk(inp4, msk4, tgt4, chunk * 2, lsum, msum);
        }
    }

    // wave (64-lane) butterfly reduction
    #pragma unroll
    for (int off = 32; off > 0; off >>= 1) {
        lsum += __shfl_xor(lsum, off);
        msum += __shfl_xor(msum, off);
    }

    __shared__ float sL[BLOCK / 64];
    __shared__ float sM[BLOCK / 64];
    const int wave = threadIdx.x >> 6;
    const int lane = threadIdx.x & 63;
    if (lane == 0) { sL[wave] = lsum; sM[wave] = msum; }
    __syncthreads();

    if (threadIdx.x == 0) {
        float bl = 0.0f, bm = 0.0f;
        #pragma unroll
        for (int i = 0; i < BLOCK / 64; ++i) { bl += sL[i]; bm += sM[i]; }
        partials[blockIdx.y * BLOCKS_X + blockIdx.x] = make_float2(bl, bm);
    }
}

__global__ __launch_bounds__(BLOCK) void bfl_reduce(
    const float2* __restrict__ partials,
    float*        __restrict__ out)
{
    float ls = 0.0f, ms = 0.0f;
    #pragma unroll
    for (int i = 0; i < NUM_PARTIALS / BLOCK; ++i) {
        const float2 p = partials[i * BLOCK + threadIdx.x];
        ls += p.x; ms += p.y;
    }

    #pragma unroll
    for (int off = 32; off > 0; off >>= 1) {
        ls += __shfl_xor(ls, off);
        ms += __shfl_xor(ms, off);
    }

    __shared__ float sL[BLOCK / 64];
    __shared__ float sM[BLOCK / 64];
    const int wave = threadIdx.x >> 6;
    const int lane = threadIdx.x & 63;
    if (lane == 0) { sL[wave] = ls; sM[wave] = ms; }
    __syncthreads();

    if (threadIdx.x == 0) {
        float bl = 0.0f, bm = 0.0f;
        #pragma unroll
        for (int i = 0; i < BLOCK / 64; ++i) { bl += sL[i]; bm += sM[i]; }
        out[0] = (bm > 0.0f) ? (bl / bm) : 0.0f;
    }
}

extern "C" void kernel_launch(void* const* d_in, const int* in_sizes, int n_in,
                              void* d_out, int out_size, void* d_ws, size_t ws_size,
                              hipStream_t stream) {
    const float* inputs   = (const float*)d_in[0];
    const int*   targets  = (const int*)d_in[1];
    const float* mask     = (const float*)d_in[2];
    float*       out      = (float*)d_out;
    float2*      partials = (float2*)d_ws;

    dim3 grid(BLOCKS_X, B_DIM);
    bfl_main<<<grid, BLOCK, 0, stream>>>(inputs, targets, mask, partials);
    bfl_reduce<<<1, BLOCK, 0, stream>>>(partials, out);
}

// Round 5
// 286.463 us; speedup vs baseline: 1.4047x; 1.4047x over previous
//
#include <hip/hip_runtime.h>
#include <math.h>

// BoundaryFocalLoss: B=128, T=200000, f32 inputs, i32 targets, f32 mask -> scalar f32.
// ~307 MB footprint; L3 serves ~half (FETCH ~155 MB). Machine sustains >=2.5 TB/s
// on this pattern (R4 datum), VALU-issue floor ~39 us (R3 VALUBusy*dur).
//
// R1: 654 us = same-address atomic serialization -> partials + 2nd kernel (124 us).
// R2: latency-bound (16% HBM, 4 blocks/CU). R3: 2560 blocks -> 119 us, VGPR=28:
//   compiler serialized the 8 chunk loads into reg-reuse groups (no MLP).
// R4: __launch_bounds__(256,8) 64-VGPR cap -> arrays spilled to scratch
//   (WRITE_SIZE 263 MB, FETCH 2x) -> 228 us. NEVER cap below working set.
// R5: no cap; named-register Chunk (nothing indexable -> nothing spillable);
//   explicit prefetch pipeline (load k+1 before compute k, 8 loads in flight);
//   2048 blocks exact fill; tail folded in via addr-clamp + scale*mask.

#define B_DIM 128
#define T_DIM 200000

constexpr int BLOCK          = 256;
constexpr int GROUPS_PER_ROW = T_DIM / 4;            // 50000 int4/float4 groups
constexpr int CHUNKS_PER_ROW = T_DIM / 8;            // 25000 8-elem chunks
constexpr int BLOCKS_X       = 16;                   // 16*128 = 2048 blocks = 8192 waves
constexpr int ROW_STRIDE_CH  = BLOCKS_X * BLOCK;     // 4096 chunks per sweep
constexpr int STEP_G         = ROW_STRIDE_CH * 2;    // 8192 groups per sweep
constexpr int FULL_ITERS     = CHUNKS_PER_ROW / ROW_STRIDE_CH;  // 6
constexpr int LAST_Q         = GROUPS_PER_ROW - 2;   // 49998 = last valid chunk-base group
constexpr int NUM_PARTIALS   = BLOCKS_X * B_DIM;     // 2048

struct Chunk {
    float4 x0, x1, m0, m1;
    int4   c0, c1, pv, nx;
};

__device__ __forceinline__ Chunk load_chunk(const float4* __restrict__ pi,
                                            const float4* __restrict__ pm,
                                            const int4*   __restrict__ pt,
                                            int q)
{
    Chunk c;
    const int qp = (q > 0) ? (q - 1) : 0;
    const int qn = (q + 2 < GROUPS_PER_ROW) ? (q + 2) : (GROUPS_PER_ROW - 1);
    c.x0 = pi[q];
    c.x1 = pi[q + 1];
    c.m0 = pm[q];
    c.m1 = pm[q + 1];
    c.c0 = pt[q];
    c.c1 = pt[q + 1];
    c.pv = pt[qp];
    c.nx = pt[qn];
    return c;
}

__device__ __forceinline__ void compute_chunk(const Chunk& ch, int q, float scale,
                                              float& lsum, float& msum)
{
    // Edge value fixes: replicate so edge transition bits compare-equal -> 0,
    // matching the reference's zero-padded trans[0] and 'SAME' window clipping.
    int4 pv = ch.pv, nx = ch.nx;
    if (q == 0) { pv.x = ch.c0.x; pv.y = ch.c0.x; pv.z = ch.c0.x; pv.w = ch.c0.x; }
    if (q + 2 >= GROUPS_PER_ROW) { nx.x = ch.c1.w; nx.y = ch.c1.w; nx.z = ch.c1.w; }

    // transition bits: bit k <-> trans at j = t0 - 4 + k, k = 1..14
    unsigned mb = 0u;
    mb |= (pv.y    != pv.x   ) ? 0x0002u : 0u;
    mb |= (pv.z    != pv.y   ) ? 0x0004u : 0u;
    mb |= (pv.w    != pv.z   ) ? 0x0008u : 0u;
    mb |= (ch.c0.x != pv.w   ) ? 0x0010u : 0u;
    mb |= (ch.c0.y != ch.c0.x) ? 0x0020u : 0u;
    mb |= (ch.c0.z != ch.c0.y) ? 0x0040u : 0u;
    mb |= (ch.c0.w != ch.c0.z) ? 0x0080u : 0u;
    mb |= (ch.c1.x != ch.c0.w) ? 0x0100u : 0u;
    mb |= (ch.c1.y != ch.c1.x) ? 0x0200u : 0u;
    mb |= (ch.c1.z != ch.c1.y) ? 0x0400u : 0u;
    mb |= (ch.c1.w != ch.c1.z) ? 0x0800u : 0u;
    mb |= (nx.x    != ch.c1.w) ? 0x1000u : 0u;
    mb |= (nx.y    != nx.x   ) ? 0x2000u : 0u;
    mb |= (nx.z    != nx.y   ) ? 0x4000u : 0u;
    // window-OR: o[k] = OR of mb[k..k+6]; boundary for element ii = bit (ii+1)
    unsigned o = mb | (mb >> 1);
    o |= o >> 2;
    o |= o >> 3;

    auto elem = [&](float x, float mm_raw, int t, int bitpos) {
        const float mm   = mm_raw * scale;
        const float posf = (((float)t) > 0.5f) ? 1.0f : 0.0f;

        const float smoothed = fmaf(posf, 0.95f, 0.025f);   // pos*(1-ls)+ls/2
        const float alpha_w  = fmaf(posf, -0.5f, 0.75f);    // 0.25 pos + 0.75 neg
        const float bf = (float)((o >> bitpos) & 1u);
        const float w  = fmaf(bf, 4.0f, 1.0f);              // 1 or 5

        // ea = exp(-|x|); sigmoid(|x|) = 1/(1+ea); |sigmoid(x)-0.5| = sigmoid(|x|)-0.5
        const float ea   = __expf(-fabsf(x));
        const float opea = 1.0f + ea;
        const float r    = __builtin_amdgcn_rcpf(opea);
        const float adaptive = 1.5f - r;

        const float bce = fmaf(-x, smoothed, fmaxf(x, 0.0f)) + __logf(opea);
        const float pt  = __expf(-bce);
        const float om  = 1.0f - pt;

        lsum = fmaf(alpha_w * om * om * bce * w * adaptive, mm, lsum);
        msum += mm;
    };

    elem(ch.x0.x, ch.m0.x, ch.c0.x, 1);
    elem(ch.x0.y, ch.m0.y, ch.c0.y, 2);
    elem(ch.x0.z, ch.m0.z, ch.c0.z, 3);
    elem(ch.x0.w, ch.m0.w, ch.c0.w, 4);
    elem(ch.x1.x, ch.m1.x, ch.c1.x, 5);
    elem(ch.x1.y, ch.m1.y, ch.c1.y, 6);
    elem(ch.x1.z, ch.m1.z, ch.c1.z, 7);
    elem(ch.x1.w, ch.m1.w, ch.c1.w, 8);
}

__global__ __launch_bounds__(BLOCK) void bfl_main(
    const float* __restrict__ inputs,
    const int*   __restrict__ targets,
    const float* __restrict__ mask,
    float2*      __restrict__ partials)   // [NUM_PARTIALS] = (loss_sum, mask_sum)
{
    const int b = blockIdx.y;
    const long long row = (long long)b * T_DIM;
    const float4* __restrict__ pi = (const float4*)(inputs + row);
    const float4* __restrict__ pm = (const float4*)(mask + row);
    const int4*   __restrict__ pt = (const int4*)(targets + row);

    const int base2 = (blockIdx.x * BLOCK + threadIdx.x) * 2;  // group idx of my chunk

    float lsum = 0.0f, msum = 0.0f;

    int q = base2;
    Chunk cur = load_chunk(pi, pm, pt, q);

    #pragma unroll
    for (int iter = 0; iter < FULL_ITERS + 1; ++iter) {
        Chunk nxt;
        const int qn = q + STEP_G;
        if (iter < FULL_ITERS) {
            // tail prefetch (iter == FULL_ITERS-1): clamp invalid lanes to group 0
            const int qc = (iter == FULL_ITERS - 1)
                ? ((qn <= LAST_Q) ? qn : 0)
                : qn;
            nxt = load_chunk(pi, pm, pt, qc);
        }
        if (iter == FULL_ITERS) {
            // tail compute: zero contributions of invalid lanes via the mask
            const bool  valid = (q <= LAST_Q);
            const float scale = valid ? 1.0f : 0.0f;
            compute_chunk(cur, valid ? q : 0, scale, lsum, msum);
        } else {
            compute_chunk(cur, q, 1.0f, lsum, msum);
        }
        cur = nxt;
        q = qn;
    }

    // wave (64-lane) butterfly reduction
    #pragma unroll
    for (int off = 32; off > 0; off >>= 1) {
        lsum += __shfl_xor(lsum, off);
        msum += __shfl_xor(msum, off);
    }

    __shared__ float sL[BLOCK / 64];
    __shared__ float sM[BLOCK / 64];
    const int wave = threadIdx.x >> 6;
    const int lane = threadIdx.x & 63;
    if (lane == 0) { sL[wave] = lsum; sM[wave] = msum; }
    __syncthreads();

    if (threadIdx.x == 0) {
        float bl = 0.0f, bm = 0.0f;
        #pragma unroll
        for (int i = 0; i < BLOCK / 64; ++i) { bl += sL[i]; bm += sM[i]; }
        partials[blockIdx.y * BLOCKS_X + blockIdx.x] = make_float2(bl, bm);
    }
}

__global__ __launch_bounds__(BLOCK) void bfl_reduce(
    const float2* __restrict__ partials,
    float*        __restrict__ out)
{
    float ls = 0.0f, ms = 0.0f;
    #pragma unroll
    for (int i = 0; i < NUM_PARTIALS / BLOCK; ++i) {
        const float2 p = partials[i * BLOCK + threadIdx.x];
        ls += p.x; ms += p.y;
    }

    #pragma unroll
    for (int off = 32; off > 0; off >>= 1) {
        ls += __shfl_xor(ls, off);
        ms += __shfl_xor(ms, off);
    }

    __shared__ float sL[BLOCK / 64];
    __shared__ float sM[BLOCK / 64];
    const int wave = threadIdx.x >> 6;
    const int lane = threadIdx.x & 63;
    if (lane == 0) { sL[wave] = ls; sM[wave] = ms; }
    __syncthreads();

    if (threadIdx.x == 0) {
        float bl = 0.0f, bm = 0.0f;
        #pragma unroll
        for (int i = 0; i < BLOCK / 64; ++i) { bl += sL[i]; bm += sM[i]; }
        out[0] = (bm > 0.0f) ? (bl / bm) : 0.0f;
    }
}

extern "C" void kernel_launch(void* const* d_in, const int* in_sizes, int n_in,
                              void* d_out, int out_size, void* d_ws, size_t ws_size,
                              hipStream_t stream) {
    const float* inputs   = (const float*)d_in[0];
    const int*   targets  = (const int*)d_in[1];
    const float* mask     = (const float*)d_in[2];
    float*       out      = (float*)d_out;
    float2*      partials = (float2*)d_ws;

    dim3 grid(BLOCKS_X, B_DIM);
    bfl_main<<<grid, BLOCK, 0, stream>>>(inputs, targets, mask, partials);
    bfl_reduce<<<1, BLOCK, 0, stream>>>(partials, out);
}